// Round 11
// baseline (110.602 us; speedup 1.0000x reference)
//
#include <hip/hip_runtime.h>

// (B,C,H,W) = (4,64,64,64) -> N=4096, Cr=8. Single-head attn, d_k=8, d_v=64.
#define BB 4
#define CC 64
#define NN 4096
#define LOG2E 1.44269504088896340736f

typedef __attribute__((ext_vector_type(8)))  short short8;
typedef __attribute__((ext_vector_type(4)))  short short4v;
typedef __attribute__((ext_vector_type(4)))  float f32x4;
typedef __attribute__((ext_vector_type(16))) float f32x16;
typedef unsigned short u16;

// workspace (all bf16):
//   qws [B*N][8]  (pre-scaled by log2e)
//   kws [B*N][8]
//   vws [B][N/4][64][4]  interleaved: elem (b,m,c) at b*262144 + (m>>2)*256 + c*4 + (m&3)
#define QWS_ELEMS (BB * NN * 8)

__device__ inline u16 f2bf(float x) {
    unsigned u = __float_as_uint(x);
    u = (u + 0x7fffu + ((u >> 16) & 1u)) >> 16;   // RNE
    return (u16)u;
}
__device__ inline unsigned pack2rne(float a, float b) {
    return (unsigned)f2bf(a) | ((unsigned)f2bf(b) << 16);
}
// truncating bf16 pack of two floats in one v_perm_b32 (P only; 6x error headroom)
__device__ inline unsigned permpack(float lo, float hi) {
    return __builtin_amdgcn_perm(__float_as_uint(hi), __float_as_uint(lo), 0x07060302);
}

union SH8 {
    short8 s;
    struct Halves { short4v lo, hi; } h;
    uint4 u;
};

// ---------------------------------------------------------------------------
// Kernel 1: QKV projection, 4 output slices of 20 (block-uniform -> SGPR
// weight loads). Grid (256, 4) x 64 thr = 1024 blocks (4 waves/CU).
// y0: q[0..8)+k[0..8)+v[0..4); y1: v[4..24); y2: v[24..44); y3: v[44..64).
// x read once per slice (4x = 67 MB, L2/L3). Q pre-scaled by log2e.
// ---------------------------------------------------------------------------
__global__ __launch_bounds__(64) void proj_kernel(
    const float* __restrict__ x,
    const float* __restrict__ wq, const float* __restrict__ bq,
    const float* __restrict__ wk, const float* __restrict__ bk,
    const float* __restrict__ wv, const float* __restrict__ bv,
    u16* __restrict__ ws_u)
{
    u16* qws = ws_u;
    u16* kws = ws_u + QWS_ELEMS;
    u16* vws = ws_u + 2 * QWS_ELEMS;

    const int y   = blockIdx.y;                    // 0..3, block-uniform
    const int pix = blockIdx.x * 64 + threadIdx.x;
    const int b   = pix >> 12;
    const int n   = pix & (NN - 1);
    const float* xb = x + ((size_t)b << 18) + n;
    u16* vdst = vws + (size_t)b * 262144 + ((n >> 2) << 8) + (n & 3);

    if (y == 0) {
        float aq[8], ak[8], av[4];
#pragma unroll
        for (int i = 0; i < 8; ++i) { aq[i] = bq[i]; ak[i] = bk[i]; }
#pragma unroll
        for (int i = 0; i < 4; ++i) av[i] = bv[i];
#pragma unroll 8
        for (int c = 0; c < CC; ++c) {
            const float xv = xb[(size_t)c << 12];          // coalesced 256B/wave
#pragma unroll
            for (int i = 0; i < 8; ++i) {
                aq[i] += wq[i * CC + c] * xv;              // scalar (uniform) loads
                ak[i] += wk[i * CC + c] * xv;
            }
#pragma unroll
            for (int i = 0; i < 4; ++i)
                av[i] += wv[i * CC + c] * xv;
        }
        uint4 qp, kp;
        qp.x = pack2rne(aq[0] * LOG2E, aq[1] * LOG2E);
        qp.y = pack2rne(aq[2] * LOG2E, aq[3] * LOG2E);
        qp.z = pack2rne(aq[4] * LOG2E, aq[5] * LOG2E);
        qp.w = pack2rne(aq[6] * LOG2E, aq[7] * LOG2E);
        kp.x = pack2rne(ak[0], ak[1]); kp.y = pack2rne(ak[2], ak[3]);
        kp.z = pack2rne(ak[4], ak[5]); kp.w = pack2rne(ak[6], ak[7]);
        *(uint4*)&qws[(size_t)pix * 8] = qp;               // 16B/lane coalesced
        *(uint4*)&kws[(size_t)pix * 8] = kp;
#pragma unroll
        for (int i = 0; i < 4; ++i)
            vdst[i << 2] = f2bf(av[i]);
    } else {
        const int v0 = y * 20 - 16;                        // 4 / 24 / 44
        float av[20];
#pragma unroll
        for (int i = 0; i < 20; ++i) av[i] = bv[v0 + i];
#pragma unroll 8
        for (int c = 0; c < CC; ++c) {
            const float xv = xb[(size_t)c << 12];
#pragma unroll
            for (int i = 0; i < 20; ++i)
                av[i] += wv[(v0 + i) * CC + c] * xv;
        }
#pragma unroll
        for (int i = 0; i < 20; ++i)
            vdst[(v0 + i) << 2] = f2bf(av[i]);
    }
}

// ---------------------------------------------------------------------------
// Kernel 2: barrier-free MFMA flash attention, XCD-L2-local + register-
// rotated prefetch. Grid 512 (1-D, swizzled): xcd = i&7 -> batch b = (i>>1)&3
// so batch b's 128 blocks land on XCDs {2b,2b+1}; per-XCD L2 working set =
// V(b) 2MB + K(b) 64KB (resident). Block 256 thr (4 waves = 4 m-quarters of
// one 32-q group). K-loop: NO LDS, NO barrier; V B-frags are coalesced
// global b64 loads (L2 hits), prefetched one 32-m tile ahead into ping-pong
// register arrays (#pragma unroll 2 -> no copies, partial vmcnt waits).
// Epilogue: 4-wave l/acc LDS tree reduction.
// ---------------------------------------------------------------------------
__global__ __launch_bounds__(256, 2) void attn_kernel(
    const float* __restrict__ x, const float* __restrict__ gamma,
    const u16* __restrict__ ws_u, float* __restrict__ out)
{
    const u16* qws = ws_u;
    const u16* kws = ws_u + QWS_ELEMS;
    const u16* vws = ws_u + 2 * QWS_ELEMS;

    __shared__ float eb[4 * 1088];     // 17408 B reduction scratch
    __shared__ float l_part[4 * 32];
    __shared__ float l_inv[32];

    const int tid  = threadIdx.x;
    const int w    = tid >> 6;     // 0..3 = m-quarter
    const int lane = tid & 63;
    const int l31  = lane & 31;
    const int lh   = lane >> 5;

    // XCD swizzle: i&7 = xcd; b from bits 1-2; qc from bits {0, 3..8}
    const int i  = blockIdx.x;
    const int b  = (i >> 1) & 3;
    const int qc = ((i >> 3) << 1) | (i & 1);   // 0..127
    const int qb = qc << 5;                     // 32 queries/block
    const int bN = b << 12;

    // Q B-frag (lanes>=32 supply k-slots 8..15 = zero; 8 real channels)
    short8 qf = {0,0,0,0,0,0,0,0};
    if (lane < 32)
        qf = *(const short8*)(qws + (size_t)(bN + qb + l31) * 8);

    // K A-frag stream: wave's m-quarter, 32 m/tile
    const u16* kp = kws + (size_t)(bN + (w << 10) + l31) * 8;

    // V B-frag geometry (interleaved layout): per 2048-u16 (32-m) window,
    // lane reads b64s at o00 (+512 | +128 | +640 | +1024 | +1536 | +1152 |
    // +1664) covering {k-half0,1} x {c-half0,1}, slot perm m=(j&3)+8(j>>2)+4lh.
    const u16* vp  = vws + (size_t)b * 262144 + (w << 16);   // quarter base
    const int  o00 = (lh << 8) + (l31 << 2);

    SH8 F[2][4];                   // ping-pong V fragments
    short8 kk[2] = {{0,0,0,0,0,0,0,0}, {0,0,0,0,0,0,0,0}};

    // tile 0 -> stage 0
    F[0][0].h.lo = *(const short4v*)(vp + o00);
    F[0][0].h.hi = *(const short4v*)(vp + o00 + 512);
    F[0][1].h.lo = *(const short4v*)(vp + o00 + 128);
    F[0][1].h.hi = *(const short4v*)(vp + o00 + 640);
    F[0][2].h.lo = *(const short4v*)(vp + o00 + 1024);
    F[0][2].h.hi = *(const short4v*)(vp + o00 + 1536);
    F[0][3].h.lo = *(const short4v*)(vp + o00 + 1152);
    F[0][3].h.hi = *(const short4v*)(vp + o00 + 1664);
    if (lane < 32) kk[0] = *(const short8*)kp;

    f32x16 z16, acc0, acc1;
#pragma unroll
    for (int r = 0; r < 16; ++r) { z16[r] = 0.f; acc0[r] = 0.f; acc1[r] = 0.f; }
    float ls = 0.f;

#pragma unroll 2
    for (int it = 0; it < 32; ++it) {
        const int cur = it & 1, nb = cur ^ 1;

        // prefetch tile it+1 into the other stage (consumed next iter; the
        // last iter reads harmless in-ws garbage, never used)
        const u16* vq = vp + (it + 1) * 2048;
        F[nb][0].h.lo = *(const short4v*)(vq + o00);
        F[nb][0].h.hi = *(const short4v*)(vq + o00 + 512);
        F[nb][1].h.lo = *(const short4v*)(vq + o00 + 128);
        F[nb][1].h.hi = *(const short4v*)(vq + o00 + 640);
        F[nb][2].h.lo = *(const short4v*)(vq + o00 + 1024);
        F[nb][2].h.hi = *(const short4v*)(vq + o00 + 1536);
        F[nb][3].h.lo = *(const short4v*)(vq + o00 + 1152);
        F[nb][3].h.hi = *(const short4v*)(vq + o00 + 1664);
        if (lane < 32) kk[nb] = *(const short8*)(kp + (it + 1) * 256);

        // S^T tile: D[m][q], lane: q=l31, 16 m (of this tile) in regs
        f32x16 d = __builtin_amdgcn_mfma_f32_32x32x16_bf16(kk[cur], qf, z16, 0, 0, 0);

        float p[16];
#pragma unroll
        for (int r = 0; r < 16; ++r) p[r] = exp2f(d[r]);   // Q pre-scaled
        float s0 = 0.f, s1 = 0.f;
#pragma unroll
        for (int r = 0; r < 8; ++r) { s0 += p[2 * r]; s1 += p[2 * r + 1]; }
        ls += s0 + s1;

        // in-register D->A repack (slot order = native reg order per lane)
        SH8 A0, A1;
        A0.u.x = permpack(p[0],  p[1]);  A0.u.y = permpack(p[2],  p[3]);
        A0.u.z = permpack(p[4],  p[5]);  A0.u.w = permpack(p[6],  p[7]);
        A1.u.x = permpack(p[8],  p[9]);  A1.u.y = permpack(p[10], p[11]);
        A1.u.z = permpack(p[12], p[13]); A1.u.w = permpack(p[14], p[15]);

        acc0 = __builtin_amdgcn_mfma_f32_32x32x16_bf16(A0.s, F[cur][0].s, acc0, 0, 0, 0);
        acc1 = __builtin_amdgcn_mfma_f32_32x32x16_bf16(A0.s, F[cur][1].s, acc1, 0, 0, 0);
        acc0 = __builtin_amdgcn_mfma_f32_32x32x16_bf16(A1.s, F[cur][2].s, acc0, 0, 0, 0);
        acc1 = __builtin_amdgcn_mfma_f32_32x32x16_bf16(A1.s, F[cur][3].s, acc1, 0, 0, 0);
    }

    // softmax denominator: lanes (l, l+32) share q=l31, disjoint m
    float lt = ls + __shfl_xor(ls, 32, 64);
    if (lane < 32) l_part[(w << 5) + l31] = lt;
    __syncthreads();
    if (w == 0 && lane < 32)
        l_inv[l31] = 1.0f / (l_part[l31] + l_part[32 + l31] +
                             l_part[64 + l31] + l_part[96 + l31]);

    // tree-reduce acc over the 4 m-quarter waves (opaque [lane][reg] blobs)
    if (w >= 2) {
        float* e0 = &eb[(((w - 2) << 1) + 0) * 1088 + lane * 17];
        float* e1 = &eb[(((w - 2) << 1) + 1) * 1088 + lane * 17];
#pragma unroll
        for (int r = 0; r < 16; ++r) { e0[r] = acc0[r]; e1[r] = acc1[r]; }
    }
    __syncthreads();
    if (w < 2) {
        const float* e0 = &eb[((w << 1) + 0) * 1088 + lane * 17];
        const float* e1 = &eb[((w << 1) + 1) * 1088 + lane * 17];
#pragma unroll
        for (int r = 0; r < 16; ++r) { acc0[r] += e0[r]; acc1[r] += e1[r]; }
    }
    __syncthreads();
    if (w == 1) {
        float* e0 = &eb[0 * 1088 + lane * 17];
        float* e1 = &eb[1 * 1088 + lane * 17];
#pragma unroll
        for (int r = 0; r < 16; ++r) { e0[r] = acc0[r]; e1[r] = acc1[r]; }
    }
    __syncthreads();
    if (w == 0) {
        const float* e0 = &eb[0 * 1088 + lane * 17];
        const float* e1 = &eb[1 * 1088 + lane * 17];
#pragma unroll
        for (int r = 0; r < 16; ++r) { acc0[r] += e0[r]; acc1[r] += e1[r]; }

        // D rows: q = 8k + 4*lh + (r&3) for regs 4k..4k+3; col c = l31 (+32)
        f32x4 li[4];
#pragma unroll
        for (int k = 0; k < 4; ++k)
            li[k] = *(const f32x4*)&l_inv[(k << 3) + (lh << 2)];
        const float g = gamma[0];
#pragma unroll
        for (int ch = 0; ch < 2; ++ch) {
            const int c = (ch << 5) + l31;
            const f32x16 a = ch ? acc1 : acc0;
            const size_t rowb = (((size_t)((b << 6) + c)) << 12) + qb;
#pragma unroll
            for (int k = 0; k < 4; ++k) {
                const int q0 = (k << 3) + (lh << 2);
                const float4 xv = *(const float4*)&x[rowb + q0];
                float4 o;
                o.x = xv.x + g * a[4 * k + 0] * li[k][0];
                o.y = xv.y + g * a[4 * k + 1] * li[k][1];
                o.z = xv.z + g * a[4 * k + 2] * li[k][2];
                o.w = xv.w + g * a[4 * k + 3] * li[k][3];
                *(float4*)&out[rowb + q0] = o;
            }
        }
    }
}

// ---------------------------------------------------------------------------
extern "C" void kernel_launch(void* const* d_in, const int* in_sizes, int n_in,
                              void* d_out, int out_size, void* d_ws, size_t ws_size,
                              hipStream_t stream)
{
    const float* x     = (const float*)d_in[0];
    const float* wq    = (const float*)d_in[1];
    const float* bq    = (const float*)d_in[2];
    const float* wk    = (const float*)d_in[3];
    const float* bk    = (const float*)d_in[4];
    const float* wv    = (const float*)d_in[5];
    const float* bv    = (const float*)d_in[6];
    const float* gamma = (const float*)d_in[7];
    u16*   ws  = (u16*)d_ws;
    float* out = (float*)d_out;

    hipLaunchKernelGGL(proj_kernel, dim3(BB * NN / 64, 4), dim3(64), 0, stream,
                       x, wq, bq, wk, bk, wv, bv, ws);
    hipLaunchKernelGGL(attn_kernel, dim3(512), dim3(256), 0, stream,
                       x, gamma, ws, out);
}